// Round 18
// baseline (116.720 us; speedup 1.0000x reference)
//
#include <hip/hip_runtime.h>
#include <hip/hip_bf16.h>
#include <math.h>

#define DEVI static __device__ __forceinline__

using f32x4  = __attribute__((ext_vector_type(4))) float;
using f32x16 = __attribute__((ext_vector_type(16))) float;
using s16x8  = __attribute__((ext_vector_type(8))) short;
using bf16x8 = __attribute__((ext_vector_type(8))) __bf16;
using i32x4  = __attribute__((ext_vector_type(4))) int;
using u32x2  = __attribute__((ext_vector_type(2))) unsigned int;
using u32x4  = __attribute__((ext_vector_type(4))) unsigned int;

constexpr int N   = 8192;
constexpr int KIN = 512;
constexpr int F   = 256;

DEVI unsigned f2bf(float f) {
  unsigned u = __builtin_bit_cast(unsigned, f);
  return ((u + 0x7FFFu + ((u >> 16) & 1u)) >> 16) & 0xFFFFu;
}

DEVI float bfLO(unsigned u) { return __builtin_bit_cast(float, (u & 0xFFFFu) << 16); }
DEVI float bfHI(unsigned u) { return __builtin_bit_cast(float, u & 0xFFFF0000u); }

DEVI unsigned cvtpk(float lo, float hi) {
  unsigned r;
  asm("v_cvt_pk_bf16_f32 %0, %1, %2" : "=v"(r) : "v"(lo), "v"(hi));
  return r;
}

DEVI f32x16 mfma32(s16x8 a, s16x8 b, f32x16 c) {
  return __builtin_amdgcn_mfma_f32_32x32x16_bf16(
      __builtin_bit_cast(bf16x8, a), __builtin_bit_cast(bf16x8, b), c, 0, 0, 0);
}

DEVI void gload16(const void* g, void* lds_uniform) {
  __builtin_amdgcn_global_load_lds(
      (const __attribute__((address_space(1))) unsigned*)g,
      (__attribute__((address_space(3))) unsigned*)lds_uniform, 16, 0, 0);
}

// ---------------- W [512][256] f32 -> Wt [256][512] bf16 (transposed) -----------
__global__ __launch_bounds__(256) void k_prep_w(const float* __restrict__ W,
                                                unsigned short* __restrict__ Wt) {
  int t = blockIdx.x * 256 + threadIdx.x;   // 16384 threads
  int c = t >> 6, k0 = (t & 63) * 8;
  s16x8 o;
#pragma unroll
  for (int i = 0; i < 8; ++i) o[i] = (short)f2bf(W[(size_t)(k0 + i) * F + c]);
  *(s16x8*)(Wt + (size_t)c * KIN + k0) = o;
}

// ---------------- h = X @ Wt^T (cast fused) : Hj + E/E5/FG ----------------------
__global__ __launch_bounds__(512) void k_gemm1(const float* __restrict__ input,
                                               const unsigned short* __restrict__ Wt,
                                               const float* __restrict__ a_vec,
                                               unsigned short* __restrict__ Hj,
                                               float* __restrict__ E, float* __restrict__ E5,
                                               unsigned* __restrict__ FG) {
  __shared__ __align__(16) char lds[8192 + 32768 + 2048];
  char* ldsA = lds;                 // [32 rows][256 B] f32 (16B-unit XOR-swizzled)
  char* ldsW = lds + 8192;          // [256 cols][128 B] bf16 (XOR-swizzled)
  float* red = (float*)(lds + 8192 + 32768); // [2][32][8]
  int tid = threadIdx.x, w = tid >> 6, l = tid & 63;
  int r0 = blockIdx.x * 32;
  f32x16 acc;
#pragma unroll
  for (int i = 0; i < 16; ++i) acc[i] = 0.f;

  int lrow8 = l >> 3;
  int koffB = ((l & 7) ^ lrow8) * 8;
  int ra = l & 31, kb = (l >> 5) * 8;
  int colw = w * 32 + ra;

  const int arow = tid >> 4, ac16 = tid & 15;
  const int aoff = (ac16 * 4) ^ ((arow & 7) << 2);
  const float* aR = input + (size_t)(r0 + arow) * KIN + aoff;

  for (int it = 0; it < 8; ++it) {
    int k0 = it * 64;
    __syncthreads();
    gload16(aR + k0, ldsA + w * 1024);
#pragma unroll
    for (int qi = 0; qi < 4; ++qi) {
      int q = 4 * w + qi;
      int c = 8 * q + lrow8;
      gload16(Wt + (size_t)c * KIN + k0 + koffB, ldsW + q * 1024);
    }
    __syncthreads();
    s16x8 av[4], bv[4];
#pragma unroll
    for (int kf = 0; kf < 4; ++kf) {
      int e4 = (kf * 16 + kb) * 4;
      f32x4 a0 = *(const f32x4*)(ldsA + ra * 256 + (e4 ^ ((ra & 7) << 4)));
      f32x4 a1 = *(const f32x4*)(ldsA + ra * 256 + ((e4 + 16) ^ ((ra & 7) << 4)));
      u32x4 ap;
      ap[0] = cvtpk(a0[0], a0[1]); ap[1] = cvtpk(a0[2], a0[3]);
      ap[2] = cvtpk(a1[0], a1[1]); ap[3] = cvtpk(a1[2], a1[3]);
      av[kf] = __builtin_bit_cast(s16x8, ap);
      int kk2 = (kf * 16 + kb) * 2;
      bv[kf] = *(const s16x8*)(ldsW + colw * 128 + (kk2 ^ ((colw & 7) << 4)));
    }
#pragma unroll
    for (int kf = 0; kf < 4; ++kf) acc = mfma32(av[kf], bv[kf], acc);
  }

  float a1v = a_vec[colw], a2v = a_vec[256 + colw];
  int rquad = (l >> 5) * 4;
#pragma unroll
  for (int g = 0; g < 4; ++g) {
    int jj = r0 + g * 8 + rquad;
    unsigned h0 = f2bf(acc[g * 4 + 0]), h1 = f2bf(acc[g * 4 + 1]);
    unsigned h2 = f2bf(acc[g * 4 + 2]), h3 = f2bf(acc[g * 4 + 3]);
    u32x2 pk;
    pk[0] = h0 | (h1 << 16);
    pk[1] = h2 | (h3 << 16);
    *(u32x2*)(Hj + ((size_t)(jj >> 4)) * 4096 + colw * 16 + (jj & 15)) = pk;
  }
#pragma unroll
  for (int g = 0; g < 16; ++g) {
    float vs = acc[g] * a1v;
    float vn = acc[g] * a2v;
#pragma unroll
    for (int m = 1; m <= 16; m <<= 1) {
      vs += __shfl_xor(vs, m, 64);
      vn += __shfl_xor(vn, m, 64);
    }
    if ((l & 31) == 0) {
      int row = (g & 3) + 8 * (g >> 2) + rquad;
      red[row * 8 + w] = vs;
      red[256 + row * 8 + w] = vn;
    }
  }
  __syncthreads();
  if (tid < 32) {
    float s = 0.f, n2 = 0.f;
#pragma unroll
    for (int i = 0; i < 8; ++i) { s += red[tid * 8 + i]; n2 += red[256 + tid * 8 + i]; }
    E[r0 + tid]  = expf(s);
    E5[r0 + tid] = expf(0.2f * s);
    FG[r0 + tid] = f2bf(expf(n2)) | (f2bf(expf(0.2f * n2)) << 16);
  }
}

// ---------------- fused masked-softmax-numerator @ h: BK=128, 16 iters ----------
// R17 structure (B direct-from-L2, P-only LDS) with BK doubled to 128 j/iter:
// HALVES the barrier-iteration count (16384 -> 8192 block-iters chip-wide) at
// unchanged occupancy (LDS 16KB, 2 blocks/CU) - attacks the per-iteration fixed
// sync cost isolated by R13/R15/R17 nulls. P buffer [64 rows][256B] with
// (r&15)<<4 swizzle (bijective; <=2-way bank conflicts). B frags in 4 pipelined
// clusters of {4 loads + 2 A ds_reads + 4 MFMA} so only ~2 clusters of B regs
// are live. Producer covers 16 j/thread; depth-1 pf (4 i32x4 + 4 u32x4).
__global__ __launch_bounds__(512, 4) void k_phase2(const int* __restrict__ adj,
                                                   const unsigned short* __restrict__ Hj,
                                                   const float* __restrict__ E,
                                                   const float* __restrict__ E5,
                                                   const unsigned* __restrict__ FG,
                                                   unsigned short* __restrict__ pacc,
                                                   float* __restrict__ ps) {
  __shared__ __align__(16) char ldsP[16384];   // [64 rows][128 j] bf16, swizzled

  const int tid = threadIdx.x, w = tid >> 6, l = tid & 63;
  const int rb = blockIdx.x >> 2, ks = blockIdx.x & 3;
  const int r0 = rb * 64;
  const int jb = ks * 2048;

  // producer role: row r, 16-j chunk jc16
  const int r = tid >> 3, jc16 = (tid & 7) * 16;
  const float Er = E[r0 + r], E5r = E5[r0 + r];
  float s_part = 0.f;
  const int*      __restrict__ adjR = adj + (size_t)(r0 + r) * N + jb + jc16;
  const unsigned* __restrict__ fgR  = FG + jb + jc16;
  const int pswz = (r & 15) << 4;
  const int pw0 = r * 256 + ((jc16 * 2) ^ pswz);
  const int pw1 = r * 256 + ((jc16 * 2 + 16) ^ pswz);

  // consumer role: rg = row half, cp = 64-feat col pair; all 8 k-steps
  const int rg = w & 1, cp = w >> 1;
  const int ra = rg * 32 + (l & 31);
  const int khb = (l >> 5) * 16;
  const int colb = cp * 64 + (l & 31);
  const int swzA = (ra & 15) << 4;
  const int kh8 = (l >> 5) * 8;
  const unsigned short* __restrict__ HjB =
      Hj + (size_t)(jb >> 4) * 4096 + colb * 16 + kh8;

  f32x16 acc0, acc1;
#pragma unroll
  for (int i = 0; i < 16; ++i) { acc0[i] = 0.f; acc1[i] = 0.f; }

  // ---- prologue: pf(0) ----
  i32x4 ad0 = *(const i32x4*)(adjR);
  i32x4 ad1 = *(const i32x4*)(adjR + 4);
  i32x4 ad2 = *(const i32x4*)(adjR + 8);
  i32x4 ad3 = *(const i32x4*)(adjR + 12);
  u32x4 fc0 = *(const u32x4*)(fgR);
  u32x4 fc1 = *(const u32x4*)(fgR + 4);
  u32x4 fc2 = *(const u32x4*)(fgR + 8);
  u32x4 fc3 = *(const u32x4*)(fgR + 12);

  for (int it = 0; it < 16; ++it) {
    const int jn = ((it + 1) & 15) * 128;
    const unsigned short* hb = HjB + (size_t)it * 32768;

    // issue B cluster 0 (kt 0,1) early - covered by P-gen + barrier
    s16x8 b00 = *(const s16x8*)(hb);
    s16x8 b01 = *(const s16x8*)(hb + 512);
    s16x8 b10 = *(const s16x8*)(hb + 4096);
    s16x8 b11 = *(const s16x8*)(hb + 4096 + 512);

    // P-gen(it): 16 j per thread (exact LeakyReLU-exp identity)
    {
      float p0, p1, p2, p3, p4, p5, p6, p7;
      u32x4 pka, pkb;
      p0 = (ad0[0] != 0) ? fmaxf(Er * bfLO(fc0[0]), E5r * bfHI(fc0[0])) : 0.f;
      p1 = (ad0[1] != 0) ? fmaxf(Er * bfLO(fc0[1]), E5r * bfHI(fc0[1])) : 0.f;
      p2 = (ad0[2] != 0) ? fmaxf(Er * bfLO(fc0[2]), E5r * bfHI(fc0[2])) : 0.f;
      p3 = (ad0[3] != 0) ? fmaxf(Er * bfLO(fc0[3]), E5r * bfHI(fc0[3])) : 0.f;
      p4 = (ad1[0] != 0) ? fmaxf(Er * bfLO(fc1[0]), E5r * bfHI(fc1[0])) : 0.f;
      p5 = (ad1[1] != 0) ? fmaxf(Er * bfLO(fc1[1]), E5r * bfHI(fc1[1])) : 0.f;
      p6 = (ad1[2] != 0) ? fmaxf(Er * bfLO(fc1[2]), E5r * bfHI(fc1[2])) : 0.f;
      p7 = (ad1[3] != 0) ? fmaxf(Er * bfLO(fc1[3]), E5r * bfHI(fc1[3])) : 0.f;
      s_part += ((p0 + p1) + (p2 + p3)) + ((p4 + p5) + (p6 + p7));
      pka[0] = cvtpk(p0, p1); pka[1] = cvtpk(p2, p3);
      pka[2] = cvtpk(p4, p5); pka[3] = cvtpk(p6, p7);
      p0 = (ad2[0] != 0) ? fmaxf(Er * bfLO(fc2[0]), E5r * bfHI(fc2[0])) : 0.f;
      p1 = (ad2[1] != 0) ? fmaxf(Er * bfLO(fc2[1]), E5r * bfHI(fc2[1])) : 0.f;
      p2 = (ad2[2] != 0) ? fmaxf(Er * bfLO(fc2[2]), E5r * bfHI(fc2[2])) : 0.f;
      p3 = (ad2[3] != 0) ? fmaxf(Er * bfLO(fc2[3]), E5r * bfHI(fc2[3])) : 0.f;
      p4 = (ad3[0] != 0) ? fmaxf(Er * bfLO(fc3[0]), E5r * bfHI(fc3[0])) : 0.f;
      p5 = (ad3[1] != 0) ? fmaxf(Er * bfLO(fc3[1]), E5r * bfHI(fc3[1])) : 0.f;
      p6 = (ad3[2] != 0) ? fmaxf(Er * bfLO(fc3[2]), E5r * bfHI(fc3[2])) : 0.f;
      p7 = (ad3[3] != 0) ? fmaxf(Er * bfLO(fc3[3]), E5r * bfHI(fc3[3])) : 0.f;
      s_part += ((p0 + p1) + (p2 + p3)) + ((p4 + p5) + (p6 + p7));
      pkb[0] = cvtpk(p0, p1); pkb[1] = cvtpk(p2, p3);
      pkb[2] = cvtpk(p4, p5); pkb[3] = cvtpk(p6, p7);
      *(u32x4*)(ldsP + pw0) = pka;
      *(u32x4*)(ldsP + pw1) = pkb;
    }

    // pf(it+1) into the now-dead registers (wrap at tail: harmless dead load)
    ad0 = *(const i32x4*)(adjR + jn);
    ad1 = *(const i32x4*)(adjR + jn + 4);
    ad2 = *(const i32x4*)(adjR + jn + 8);
    ad3 = *(const i32x4*)(adjR + jn + 12);
    fc0 = *(const u32x4*)(fgR + jn);
    fc1 = *(const u32x4*)(fgR + jn + 4);
    fc2 = *(const u32x4*)(fgR + jn + 8);
    fc3 = *(const u32x4*)(fgR + jn + 12);

    // P write visible to all waves
    asm volatile("s_waitcnt lgkmcnt(0)" ::: "memory");
    __builtin_amdgcn_s_barrier();

    // pipelined consume: 4 clusters of {issue next B, 2 A reads, 4 MFMA}
    {
      s16x8 b20 = *(const s16x8*)(hb + 8192);
      s16x8 b21 = *(const s16x8*)(hb + 8192 + 512);
      s16x8 b30 = *(const s16x8*)(hb + 12288);
      s16x8 b31 = *(const s16x8*)(hb + 12288 + 512);
      s16x8 a0 = *(const s16x8*)(ldsP + ra * 256 + ((0 * 32 + khb) ^ swzA));
      s16x8 a1 = *(const s16x8*)(ldsP + ra * 256 + ((1 * 32 + khb) ^ swzA));
      __builtin_amdgcn_s_setprio(1);
      acc0 = mfma32(a0, b00, acc0);
      acc1 = mfma32(a0, b01, acc1);
      acc0 = mfma32(a1, b10, acc0);
      acc1 = mfma32(a1, b11, acc1);
      __builtin_amdgcn_s_setprio(0);

      s16x8 b40 = *(const s16x8*)(hb + 16384);
      s16x8 b41 = *(const s16x8*)(hb + 16384 + 512);
      s16x8 b50 = *(const s16x8*)(hb + 20480);
      s16x8 b51 = *(const s16x8*)(hb + 20480 + 512);
      s16x8 a2 = *(const s16x8*)(ldsP + ra * 256 + ((2 * 32 + khb) ^ swzA));
      s16x8 a3 = *(const s16x8*)(ldsP + ra * 256 + ((3 * 32 + khb) ^ swzA));
      __builtin_amdgcn_s_setprio(1);
      acc0 = mfma32(a2, b20, acc0);
      acc1 = mfma32(a2, b21, acc1);
      acc0 = mfma32(a3, b30, acc0);
      acc1 = mfma32(a3, b31, acc1);
      __builtin_amdgcn_s_setprio(0);

      s16x8 b60 = *(const s16x8*)(hb + 24576);
      s16x8 b61 = *(const s16x8*)(hb + 24576 + 512);
      s16x8 b70 = *(const s16x8*)(hb + 28672);
      s16x8 b71 = *(const s16x8*)(hb + 28672 + 512);
      s16x8 a4 = *(const s16x8*)(ldsP + ra * 256 + ((4 * 32 + khb) ^ swzA));
      s16x8 a5 = *(const s16x8*)(ldsP + ra * 256 + ((5 * 32 + khb) ^ swzA));
      __builtin_amdgcn_s_setprio(1);
      acc0 = mfma32(a4, b40, acc0);
      acc1 = mfma32(a4, b41, acc1);
      acc0 = mfma32(a5, b50, acc0);
      acc1 = mfma32(a5, b51, acc1);
      __builtin_amdgcn_s_setprio(0);

      s16x8 a6 = *(const s16x8*)(ldsP + ra * 256 + ((6 * 32 + khb) ^ swzA));
      s16x8 a7 = *(const s16x8*)(ldsP + ra * 256 + ((7 * 32 + khb) ^ swzA));
      __builtin_amdgcn_s_setprio(1);
      acc0 = mfma32(a6, b60, acc0);
      acc1 = mfma32(a6, b61, acc1);
      acc0 = mfma32(a7, b70, acc0);
      acc1 = mfma32(a7, b71, acc1);
      __builtin_amdgcn_s_setprio(0);
    }

    // A reads drained before next iter's P write
    asm volatile("s_waitcnt lgkmcnt(0)" ::: "memory");
    __builtin_amdgcn_s_barrier();
  }

  // ---- epilogue: partial rowsum (8 threads/row), bf16 partial acc ----
  float s = s_part;
#pragma unroll
  for (int m = 1; m <= 4; m <<= 1) s += __shfl_xor(s, m, 64);
  if ((tid & 7) == 0) ps[(size_t)ks * N + r0 + r] = s;

  unsigned short* po = pacc + (size_t)ks * N * F;
#pragma unroll
  for (int g = 0; g < 16; ++g) {
    int orow = rg * 32 + (g & 3) + 8 * (g >> 2) + 4 * (l >> 5);
    unsigned short* pr = po + (size_t)(r0 + orow) * F + colb;
    pr[0]  = (unsigned short)f2bf(acc0[g]);
    pr[32] = (unsigned short)f2bf(acc1[g]);
  }
}

// ---------------- combine 4 bf16 split-K partials, normalize, ELU ---------------
__global__ __launch_bounds__(256) void k_combine(const unsigned short* __restrict__ pacc,
                                                 const float* __restrict__ ps,
                                                 float* __restrict__ out) {
  int t = blockIdx.x * 256 + threadIdx.x;  // 524288 threads, 4 feats each
  size_t idx = (size_t)t * 4;
  int row = (int)(idx >> 8);
  f32x4 sum;
#pragma unroll
  for (int i = 0; i < 4; ++i) sum[i] = 0.f;
#pragma unroll
  for (int k = 0; k < 4; ++k) {
    u32x2 q = *(const u32x2*)(pacc + (size_t)k * N * F + idx);
    sum[0] += bfLO(q[0]); sum[1] += bfHI(q[0]);
    sum[2] += bfLO(q[1]); sum[3] += bfHI(q[1]);
  }
  float inv = 1.f / (ps[row] + ps[N + row] + ps[2 * N + row] + ps[3 * N + row]);
  f32x4 o;
#pragma unroll
  for (int i = 0; i < 4; ++i) {
    float v = sum[i] * inv;
    o[i] = v > 0.f ? v : expm1f(v);
  }
  *(f32x4*)(out + idx) = o;
}

extern "C" void kernel_launch(void* const* d_in, const int* in_sizes, int n_in,
                              void* d_out, int out_size, void* d_ws, size_t ws_size,
                              hipStream_t stream) {
  const float* input = (const float*)d_in[0];
  const int*   adj   = (const int*)d_in[1];
  const float* W     = (const float*)d_in[2];
  const float* a     = (const float*)d_in[3];
  float* out = (float*)d_out;
  char* ws = (char*)d_ws;

  // pacc (16 MB, bf16) aliases Wt (dead before k_phase2 runs).
  unsigned short* pacc = (unsigned short*)(ws);              // 16,777,216 B @0
  unsigned short* Wt   = (unsigned short*)(ws + 8388608);    //    262,144 B
  unsigned short* Hj   = (unsigned short*)(ws + 16777216);   //  4,194,304 B
  float*    E  = (float*)(ws + 20971520);                    //     32,768 B
  float*    E5 = (float*)(ws + 21004288);                    //     32,768 B
  unsigned* FG = (unsigned*)(ws + 21037056);                 //     32,768 B
  float*    ps = (float*)(ws + 21069824);                    //    131,072 B -> 21.2 MB

  hipLaunchKernelGGL(k_prep_w, dim3(64),   dim3(256), 0, stream, W, Wt);
  hipLaunchKernelGGL(k_gemm1,  dim3(256),  dim3(512), 0, stream, input, Wt, a, Hj, E, E5, FG);
  hipLaunchKernelGGL(k_phase2, dim3(512),  dim3(512), 0, stream, adj, Hj, E, E5, FG, pacc, ps);
  hipLaunchKernelGGL(k_combine,dim3(2048), dim3(256), 0, stream, pacc, ps, out);
}

// Round 19
// 112.649 us; speedup vs baseline: 1.0361x; 1.0361x over previous
//
#include <hip/hip_runtime.h>
#include <hip/hip_bf16.h>
#include <math.h>

#define DEVI static __device__ __forceinline__

using f32x4  = __attribute__((ext_vector_type(4))) float;
using f32x16 = __attribute__((ext_vector_type(16))) float;
using s16x8  = __attribute__((ext_vector_type(8))) short;
using bf16x8 = __attribute__((ext_vector_type(8))) __bf16;
using i32x4  = __attribute__((ext_vector_type(4))) int;
using u32x2  = __attribute__((ext_vector_type(2))) unsigned int;
using u32x4  = __attribute__((ext_vector_type(4))) unsigned int;

constexpr int N   = 8192;
constexpr int KIN = 512;
constexpr int F   = 256;

DEVI unsigned f2bf(float f) {
  unsigned u = __builtin_bit_cast(unsigned, f);
  return ((u + 0x7FFFu + ((u >> 16) & 1u)) >> 16) & 0xFFFFu;
}

DEVI float bfLO(unsigned u) { return __builtin_bit_cast(float, (u & 0xFFFFu) << 16); }
DEVI float bfHI(unsigned u) { return __builtin_bit_cast(float, u & 0xFFFF0000u); }

DEVI unsigned cvtpk(float lo, float hi) {
  unsigned r;
  asm("v_cvt_pk_bf16_f32 %0, %1, %2" : "=v"(r) : "v"(lo), "v"(hi));
  return r;
}

DEVI f32x16 mfma32(s16x8 a, s16x8 b, f32x16 c) {
  return __builtin_amdgcn_mfma_f32_32x32x16_bf16(
      __builtin_bit_cast(bf16x8, a), __builtin_bit_cast(bf16x8, b), c, 0, 0, 0);
}

DEVI void gload16(const void* g, void* lds_uniform) {
  __builtin_amdgcn_global_load_lds(
      (const __attribute__((address_space(1))) unsigned*)g,
      (__attribute__((address_space(3))) unsigned*)lds_uniform, 16, 0, 0);
}

// ---------------- W [512][256] f32 -> Wt [256][512] bf16 (transposed) -----------
__global__ __launch_bounds__(256) void k_prep_w(const float* __restrict__ W,
                                                unsigned short* __restrict__ Wt) {
  int t = blockIdx.x * 256 + threadIdx.x;   // 16384 threads
  int c = t >> 6, k0 = (t & 63) * 8;
  s16x8 o;
#pragma unroll
  for (int i = 0; i < 8; ++i) o[i] = (short)f2bf(W[(size_t)(k0 + i) * F + c]);
  *(s16x8*)(Wt + (size_t)c * KIN + k0) = o;
}

// ---------------- h = X @ Wt^T (cast fused) : Ht[256][8192] bf16 + E/E5/FG ------
// A staged as raw f32 via global_load_lds (8KB tile, source elem offset
// pre-swizzled by (row&7)<<2 so the swizzled 16B-granular read below recovers
// linear elements); converted to bf16 fragments in-register with
// v_cvt_pk_bf16_f32 (RNE - bit-identical to the old k_cast+bf16-load path).
__global__ __launch_bounds__(512) void k_gemm1(const float* __restrict__ input,
                                               const unsigned short* __restrict__ Wt,
                                               const float* __restrict__ a_vec,
                                               unsigned short* __restrict__ Ht,
                                               float* __restrict__ E, float* __restrict__ E5,
                                               unsigned* __restrict__ FG) {
  __shared__ __align__(16) char lds[8192 + 32768 + 2048];
  char* ldsA = lds;                 // [32 rows][256 B] f32 (16B-unit XOR-swizzled)
  char* ldsW = lds + 8192;          // [256 cols][128 B] bf16 (XOR-swizzled)
  float* red = (float*)(lds + 8192 + 32768); // [2][32][8]
  int tid = threadIdx.x, w = tid >> 6, l = tid & 63;
  int r0 = blockIdx.x * 32;
  f32x16 acc;
#pragma unroll
  for (int i = 0; i < 16; ++i) acc[i] = 0.f;

  int lrow8 = l >> 3;
  int koffB = ((l & 7) ^ lrow8) * 8;   // pre-swizzled source k-offset (bf16 elems)
  int ra = l & 31, kb = (l >> 5) * 8;
  int colw = w * 32 + ra;

  // A staging role: thread covers row arow, 16B chunk ac16 (4 f32)
  const int arow = tid >> 4, ac16 = tid & 15;
  const int aoff = (ac16 * 4) ^ ((arow & 7) << 2);   // pre-swizzled f32 elem off
  const float* aR = input + (size_t)(r0 + arow) * KIN + aoff;

  for (int it = 0; it < 8; ++it) {
    int k0 = it * 64;
    __syncthreads();
    // stage A (f32, 8KB): 512 threads x 16B; LDS dest linear = tid*16
    gload16(aR + k0, ldsA + w * 1024);
    // stage W (bf16, 32KB)
#pragma unroll
    for (int qi = 0; qi < 4; ++qi) {
      int q = 4 * w + qi;
      int c = 8 * q + lrow8;
      gload16(Wt + (size_t)c * KIN + k0 + koffB, ldsW + q * 1024);
    }
    __syncthreads();
    s16x8 av[4], bv[4];
#pragma unroll
    for (int kf = 0; kf < 4; ++kf) {
      int e4 = (kf * 16 + kb) * 4;        // byte offset of fragment (32B-aligned)
      f32x4 a0 = *(const f32x4*)(ldsA + ra * 256 + (e4 ^ ((ra & 7) << 4)));
      f32x4 a1 = *(const f32x4*)(ldsA + ra * 256 + ((e4 + 16) ^ ((ra & 7) << 4)));
      u32x4 ap;
      ap[0] = cvtpk(a0[0], a0[1]); ap[1] = cvtpk(a0[2], a0[3]);
      ap[2] = cvtpk(a1[0], a1[1]); ap[3] = cvtpk(a1[2], a1[3]);
      av[kf] = __builtin_bit_cast(s16x8, ap);
      int kk2 = (kf * 16 + kb) * 2;
      bv[kf] = *(const s16x8*)(ldsW + colw * 128 + (kk2 ^ ((colw & 7) << 4)));
    }
#pragma unroll
    for (int kf = 0; kf < 4; ++kf) acc = mfma32(av[kf], bv[kf], acc);
  }

  float a1v = a_vec[colw], a2v = a_vec[256 + colw];
  int rquad = (l >> 5) * 4;
#pragma unroll
  for (int g = 0; g < 4; ++g) {
    int rowb = g * 8 + rquad;
    unsigned h0 = f2bf(acc[g * 4 + 0]), h1 = f2bf(acc[g * 4 + 1]);
    unsigned h2 = f2bf(acc[g * 4 + 2]), h3 = f2bf(acc[g * 4 + 3]);
    u32x2 pk;
    pk[0] = h0 | (h1 << 16);
    pk[1] = h2 | (h3 << 16);
    *(u32x2*)(Ht + (size_t)colw * N + r0 + rowb) = pk;
  }
#pragma unroll
  for (int g = 0; g < 16; ++g) {
    float vs = acc[g] * a1v;
    float vn = acc[g] * a2v;
#pragma unroll
    for (int m = 1; m <= 16; m <<= 1) {
      vs += __shfl_xor(vs, m, 64);
      vn += __shfl_xor(vn, m, 64);
    }
    if ((l & 31) == 0) {
      int row = (g & 3) + 8 * (g >> 2) + rquad;
      red[row * 8 + w] = vs;
      red[256 + row * 8 + w] = vn;
    }
  }
  __syncthreads();
  if (tid < 32) {
    float s = 0.f, n2 = 0.f;
#pragma unroll
    for (int i = 0; i < 8; ++i) { s += red[tid * 8 + i]; n2 += red[256 + tid * 8 + i]; }
    E[r0 + tid]  = expf(s);
    E5[r0 + tid] = expf(0.2f * s);
    FG[r0 + tid] = f2bf(expf(n2)) | (f2bf(expf(0.2f * n2)) << 16);
  }
}

// ---------------- fused masked-softmax-numerator @ h: kt-split (R12, verified) --
// grid 512 = 128 row-blocks (64 rows) x KSPLIT=4; 512 threads; 2 blocks/CU
// (LDS 72KB, regs <=128 via launch_bounds(512,4)). Wave role: w = kh*4+fgp*2+rg.
// Per wave-iter: 2 A + 8 B ds_reads -> 8 MFMA. Verified best phase2 (R12/R16).
__global__ __launch_bounds__(512, 4) void k_phase2(const int* __restrict__ adj,
                                                   const unsigned short* __restrict__ Ht,
                                                   const float* __restrict__ E,
                                                   const float* __restrict__ E5,
                                                   const unsigned* __restrict__ FG,
                                                   unsigned short* __restrict__ pacc,
                                                   float* __restrict__ ps) {
  __shared__ __align__(16) char lds[65536 + 8192];
  char* ldsH = lds;            // 2 x [256 feats][64 j] bf16, swizzled (32KB each)
  char* ldsP = lds + 65536;    // 1 x [64 rows][64 j] bf16, swizzled (8KB)

  const int tid = threadIdx.x, w = tid >> 6, l = tid & 63;
  const int rb = blockIdx.x >> 2, ks = blockIdx.x & 3;
  const int r0 = rb * 64;
  const int jb = ks * 2048;

  const int r = tid >> 3, jc8 = (tid & 7) * 8;
  const float Er = E[r0 + r], E5r = E5[r0 + r];
  float s_part = 0.f;
  const int*      __restrict__ adjR = adj + (size_t)(r0 + r) * N + jb + jc8;
  const unsigned* __restrict__ fgR  = FG + jb + jc8;
  const int pw_byte = r * 128 + ((jc8 * 2) ^ ((r & 7) << 4));

  const int lrow8 = l >> 3;
  const int koffB = ((l & 7) ^ lrow8) * 8;

  const int kh = w >> 2, fgp = (w >> 1) & 1, rg = w & 1;
  const int ra = rg * 32 + (l & 31);
  const int khb = (l >> 5) * 16;
  const int colb = fgp * 128 + (l & 31);
  const int swzA = (ra & 7) << 4;
  const int swzB = (l & 7) << 4;
  const int kt0 = kh * 2;

  f32x16 acc0, acc1, acc2, acc3;
#pragma unroll
  for (int i = 0; i < 16; ++i) { acc0[i] = 0.f; acc1[i] = 0.f; acc2[i] = 0.f; acc3[i] = 0.f; }

#pragma unroll
  for (int qi = 0; qi < 4; ++qi) {
    int q = 4 * w + qi;
    int c = 8 * q + lrow8;
    gload16(Ht + (size_t)c * N + jb + koffB, ldsH + q * 1024);
  }
  i32x4 ad0 = *(const i32x4*)(adjR);
  i32x4 ad1 = *(const i32x4*)(adjR + 4);
  u32x4 fc0 = *(const u32x4*)(fgR);
  u32x4 fc1 = *(const u32x4*)(fgR + 4);

  for (int it = 0; it < 32; ++it) {
    char* Hc = ldsH + (it & 1) * 32768;
    char* Hn = ldsH + ((it & 1) ^ 1) * 32768;
    const int jn = ((it + 1) & 31) * 64;

    {
      float p0 = (ad0[0] != 0) ? fmaxf(Er * bfLO(fc0[0]), E5r * bfHI(fc0[0])) : 0.f;
      float p1 = (ad0[1] != 0) ? fmaxf(Er * bfLO(fc0[1]), E5r * bfHI(fc0[1])) : 0.f;
      float p2 = (ad0[2] != 0) ? fmaxf(Er * bfLO(fc0[2]), E5r * bfHI(fc0[2])) : 0.f;
      float p3 = (ad0[3] != 0) ? fmaxf(Er * bfLO(fc0[3]), E5r * bfHI(fc0[3])) : 0.f;
      float p4 = (ad1[0] != 0) ? fmaxf(Er * bfLO(fc1[0]), E5r * bfHI(fc1[0])) : 0.f;
      float p5 = (ad1[1] != 0) ? fmaxf(Er * bfLO(fc1[1]), E5r * bfHI(fc1[1])) : 0.f;
      float p6 = (ad1[2] != 0) ? fmaxf(Er * bfLO(fc1[2]), E5r * bfHI(fc1[2])) : 0.f;
      float p7 = (ad1[3] != 0) ? fmaxf(Er * bfLO(fc1[3]), E5r * bfHI(fc1[3])) : 0.f;
      s_part += ((p0 + p1) + (p2 + p3)) + ((p4 + p5) + (p6 + p7));
      u32x4 pk;
      pk[0] = cvtpk(p0, p1); pk[1] = cvtpk(p2, p3);
      pk[2] = cvtpk(p4, p5); pk[3] = cvtpk(p6, p7);
      *(u32x4*)(ldsP + pw_byte) = pk;
    }

    ad0 = *(const i32x4*)(adjR + jn);
    ad1 = *(const i32x4*)(adjR + jn + 4);
    fc0 = *(const u32x4*)(fgR + jn);
    fc1 = *(const u32x4*)(fgR + jn + 4);

    asm volatile("s_waitcnt vmcnt(4) lgkmcnt(0)" ::: "memory");
    __builtin_amdgcn_s_barrier();

#pragma unroll
    for (int qi = 0; qi < 4; ++qi) {
      int q = 4 * w + qi;
      int c = 8 * q + lrow8;
      gload16(Ht + (size_t)c * N + jb + jn + koffB, Hn + q * 1024);
    }

#pragma unroll
    for (int t2 = 0; t2 < 2; ++t2) {
      int kk2 = (kt0 + t2) * 32 + khb;
      s16x8 av = *(const s16x8*)(ldsP + ra * 128 + (kk2 ^ swzA));
      s16x8 b0 = *(const s16x8*)(Hc + (colb     ) * 128 + (kk2 ^ swzB));
      s16x8 b1 = *(const s16x8*)(Hc + (colb + 32) * 128 + (kk2 ^ swzB));
      s16x8 b2 = *(const s16x8*)(Hc + (colb + 64) * 128 + (kk2 ^ swzB));
      s16x8 b3 = *(const s16x8*)(Hc + (colb + 96) * 128 + (kk2 ^ swzB));
      acc0 = mfma32(av, b0, acc0);
      acc1 = mfma32(av, b1, acc1);
      acc2 = mfma32(av, b2, acc2);
      acc3 = mfma32(av, b3, acc3);
    }

    asm volatile("s_waitcnt lgkmcnt(0)" ::: "memory");
    __builtin_amdgcn_s_barrier();
  }

  float s = s_part;
#pragma unroll
  for (int m = 1; m <= 4; m <<= 1) s += __shfl_xor(s, m, 64);
  if ((tid & 7) == 0) ps[(size_t)ks * N + r0 + r] = s;

  __syncthreads();
  float* red = (float*)ldsH;
  const int rbase = (fgp * 2 + rg) * 4096;
  if (kh == 1) {
#pragma unroll
    for (int cg = 0; cg < 4; ++cg) {
      const f32x16* a = (cg == 0) ? &acc0 : (cg == 1) ? &acc1 : (cg == 2) ? &acc2 : &acc3;
#pragma unroll
      for (int q = 0; q < 4; ++q) {
        f32x4 v;
#pragma unroll
        for (int i = 0; i < 4; ++i) v[i] = (*a)[q * 4 + i];
        int boff = (cg * 64 + q * 16) ^ ((l & 7) << 4);
        *(f32x4*)((char*)&red[rbase + l * 64] + boff) = v;
      }
    }
  }
  __syncthreads();
  if (kh == 0) {
#pragma unroll
    for (int cg = 0; cg < 4; ++cg) {
      f32x16* a = (cg == 0) ? &acc0 : (cg == 1) ? &acc1 : (cg == 2) ? &acc2 : &acc3;
#pragma unroll
      for (int q = 0; q < 4; ++q) {
        int boff = (cg * 64 + q * 16) ^ ((l & 7) << 4);
        f32x4 v = *(const f32x4*)((const char*)&red[rbase + l * 64] + boff);
#pragma unroll
        for (int i = 0; i < 4; ++i) (*a)[q * 4 + i] += v[i];
      }
    }
    unsigned short* po = pacc + (size_t)ks * N * F;
#pragma unroll
    for (int g = 0; g < 16; ++g) {
      int orow = rg * 32 + (g & 3) + 8 * (g >> 2) + 4 * (l >> 5);
      unsigned short* pr = po + (size_t)(r0 + orow) * F + colb;
      pr[0]  = (unsigned short)f2bf(acc0[g]);
      pr[32] = (unsigned short)f2bf(acc1[g]);
      pr[64] = (unsigned short)f2bf(acc2[g]);
      pr[96] = (unsigned short)f2bf(acc3[g]);
    }
  }
}

// ---------------- combine 4 bf16 split-K partials, normalize, ELU ---------------
__global__ __launch_bounds__(256) void k_combine(const unsigned short* __restrict__ pacc,
                                                 const float* __restrict__ ps,
                                                 float* __restrict__ out) {
  int t = blockIdx.x * 256 + threadIdx.x;  // 524288 threads, 4 feats each
  size_t idx = (size_t)t * 4;
  int row = (int)(idx >> 8);
  f32x4 sum;
#pragma unroll
  for (int i = 0; i < 4; ++i) sum[i] = 0.f;
#pragma unroll
  for (int k = 0; k < 4; ++k) {
    u32x2 q = *(const u32x2*)(pacc + (size_t)k * N * F + idx);
    sum[0] += bfLO(q[0]); sum[1] += bfHI(q[0]);
    sum[2] += bfLO(q[1]); sum[3] += bfHI(q[1]);
  }
  float inv = 1.f / (ps[row] + ps[N + row] + ps[2 * N + row] + ps[3 * N + row]);
  f32x4 o;
#pragma unroll
  for (int i = 0; i < 4; ++i) {
    float v = sum[i] * inv;
    o[i] = v > 0.f ? v : expm1f(v);
  }
  *(f32x4*)(out + idx) = o;
}

extern "C" void kernel_launch(void* const* d_in, const int* in_sizes, int n_in,
                              void* d_out, int out_size, void* d_ws, size_t ws_size,
                              hipStream_t stream) {
  const float* input = (const float*)d_in[0];
  const int*   adj   = (const int*)d_in[1];
  const float* W     = (const float*)d_in[2];
  const float* a     = (const float*)d_in[3];
  float* out = (float*)d_out;
  char* ws = (char*)d_ws;

  // pacc (16 MB, bf16) aliases Wt (dead before k_phase2 runs).
  unsigned short* pacc = (unsigned short*)(ws);              // 16,777,216 B @0
  unsigned short* Wt   = (unsigned short*)(ws + 8388608);    //    262,144 B
  unsigned short* Ht   = (unsigned short*)(ws + 16777216);   //  4,194,304 B
  float*    E  = (float*)(ws + 20971520);                    //     32,768 B
  float*    E5 = (float*)(ws + 21004288);                    //     32,768 B
  unsigned* FG = (unsigned*)(ws + 21037056);                 //     32,768 B
  float*    ps = (float*)(ws + 21069824);                    //    131,072 B -> 21.2 MB

  hipLaunchKernelGGL(k_prep_w, dim3(64),   dim3(256), 0, stream, W, Wt);
  hipLaunchKernelGGL(k_gemm1,  dim3(256),  dim3(512), 0, stream, input, Wt, a, Ht, E, E5, FG);
  hipLaunchKernelGGL(k_phase2, dim3(512),  dim3(512), 0, stream, adj, Ht, E, E5, FG, pacc, ps);
  hipLaunchKernelGGL(k_combine,dim3(2048), dim3(256), 0, stream, pacc, ps, out);
}